// Round 3
// baseline (3062.501 us; speedup 1.0000x reference)
//
#include <hip/hip_runtime.h>
#include <hip/hip_bf16.h>
#include <math.h>
#include <type_traits>

typedef __hip_bfloat16 bf16;

#define B_    4
#define H_    128
#define W_    256
#define HW_   32768          // H_*W_
#define CTXC  172
#define GRUIN 236
#define NPIX  131072         // B_*HW_

__device__ __forceinline__ float b2f(bf16 v) { return __bfloat162float(v); }
__device__ __forceinline__ bf16  f2b(float v){ return __float2bfloat16(v); }
__device__ __forceinline__ float ldv(const float* p){ return *p; }
__device__ __forceinline__ float ldv(const bf16* p) { return b2f(*p); }

// ------------------------------------------------------------- dtype detect --
// flag=1 -> inputs are float32; flag=0 -> inputs are bf16.
__global__ void detect_k(const unsigned int* __restrict__ feat_raw,
                         int* __restrict__ flag)
{
    if (threadIdx.x != 0 || blockIdx.x != 0) return;
    int hits = 0;
    for (int i = 0; i < 64; ++i) {
        unsigned int w = feat_raw[i];
        unsigned int e = (w >> 7) & 0xFFu;     // exponent of low-half bf16
        hits += (e >= 0xC0u) ? 1 : 0;
    }
    *flag = (hits > 0) ? 1 : 0;
}

template<typename IT>
__device__ __forceinline__ bool gate_skip(const int* flag)
{
    constexpr bool isf = std::is_same<IT, float>::value;
    return (*flag != 0) != isf;
}

// ---------------------------------------------------------------- weights ---
template<typename IT>
__global__ __launch_bounds__(256) void wcvt(const int* __restrict__ flag,
                                            const IT* __restrict__ src,
                                            float* __restrict__ dst,
                                            int CO, int CI)
{
    if (gate_skip<IT>(flag)) return;
    int i = blockIdx.x * 256 + threadIdx.x;
    int n = CO * CI * 9;
    if (i >= n) return;
    int k  = i % 9;
    int t  = i / 9;
    int ci = t % CI;
    int co = t / CI;
    dst[((size_t)ci * CO + co) * 9 + k] = ldv(src + i);
}

template<typename IT>
__global__ __launch_bounds__(256) void cvt_big(const int* __restrict__ flag,
                                               const IT* __restrict__ src,
                                               bf16* __restrict__ dst, int n)
{
    if (gate_skip<IT>(flag)) return;
    int i = blockIdx.x * 256 + threadIdx.x;
    if (i < n) dst[i] = f2b(ldv(src + i));
}

// small params -> sparams layout:
// 0:zb(64) 64:rb(64) 128:qb(64) 192:g1s(48) 240:g1b(48) 288:g2s(48) 336:g2b(48)
// 384:wd(48) 432:wx(48) 480:wy(48) 528:wc(48) 576:bd 577:bx 578:by 579:bc
template<typename IT>
__global__ void cvt_small(const int* __restrict__ flag,
    const IT* zb, const IT* rb, const IT* qb,
    const IT* g1s, const IT* g1b, const IT* g2s, const IT* g2b,
    const IT* wd, const IT* wx, const IT* wy, const IT* wc,
    const IT* bd, const IT* bx, const IT* by, const IT* bc,
    bf16* __restrict__ dst)
{
    if (gate_skip<IT>(flag)) return;
    int i = blockIdx.x * 256 + threadIdx.x;
    if (i >= 580) return;
    const IT* src; int off;
    if      (i < 64)  { src = zb;  off = i; }
    else if (i < 128) { src = rb;  off = i - 64; }
    else if (i < 192) { src = qb;  off = i - 128; }
    else if (i < 240) { src = g1s; off = i - 192; }
    else if (i < 288) { src = g1b; off = i - 240; }
    else if (i < 336) { src = g2s; off = i - 288; }
    else if (i < 384) { src = g2b; off = i - 336; }
    else if (i < 432) { src = wd;  off = i - 384; }
    else if (i < 480) { src = wx;  off = i - 432; }
    else if (i < 528) { src = wy;  off = i - 480; }
    else if (i < 576) { src = wc;  off = i - 528; }
    else if (i == 576){ src = bd;  off = 0; }
    else if (i == 577){ src = bx;  off = 0; }
    else if (i == 578){ src = by;  off = 0; }
    else              { src = bc;  off = 0; }
    dst[i] = f2b(ldv(src + off));
}

// ------------------------------------------------------------------- ctx -----
// ctx channels: [fL 0..63][fR_w 64..127][d 128][sx 129][sy 130][conf 131][cost 132..171]
// dscf: 4 f32 planes of NPIX: d, sx, sy, conf (exact passthrough for heads)
template<typename IT>
__global__ __launch_bounds__(256) void build_ctx(
    const int* __restrict__ flag,
    const IT* __restrict__ d_, const IT* __restrict__ sx_,
    const IT* __restrict__ sy_, const IT* __restrict__ conf_,
    const IT* __restrict__ fL, const IT* __restrict__ fR,
    bf16* __restrict__ ctx, float* __restrict__ dscf)
{
    if (gate_skip<IT>(flag)) return;
    const int x   = threadIdx.x;
    const int blk = blockIdx.x;
    const int y   = blk & (H_ - 1);
    const int b   = blk >> 7;
    const int pix = (b << 15) | (y << 8) | x;

    const float d0 = ldv(d_ + pix);

    float xw = fminf(fmaxf((float)x - d0, 0.f), (float)(W_ - 1));
    float x0 = floorf(xw);
    float w1 = xw - x0;
    int i0 = (int)x0;
    int i1 = min(i0 + 1, W_ - 1);

    int   j0[5], j1[5];
    float wq[5];
#pragma unroll
    for (int dd = 0; dd < 5; ++dd) {
        float cd = fminf(fmaxf((float)x - d0 - (float)(dd - 2), 0.f), (float)(W_ - 1));
        float c0 = floorf(cd);
        wq[dd] = cd - c0;
        j0[dd] = (int)c0;
        j1[dd] = min(j0[dd] + 1, W_ - 1);
    }

    float cost[40];
#pragma unroll
    for (int k = 0; k < 40; ++k) cost[k] = 0.f;

    const IT* fLrow = fL + (size_t)b * 64 * HW_ + y * W_;
    const IT* fRrow = fR + (size_t)b * 64 * HW_ + y * W_;
    bf16* cbase = ctx + (size_t)b * CTXC * HW_ + y * W_ + x;

#pragma unroll
    for (int g = 0; g < 8; ++g) {
#pragma unroll
        for (int cc = 0; cc < 8; ++cc) {
            const int c = g * 8 + cc;
            const IT* fr = fRrow + (size_t)c * HW_;
            float fl = ldv(fLrow + (size_t)c * HW_ + x);
            cbase[(size_t)c * HW_] = f2b(fl);                      // fL
            float fw = ldv(fr + i0) * (1.f - w1) + ldv(fr + i1) * w1;
            cbase[(size_t)(64 + c) * HW_] = f2b(fw);               // fR_w
#pragma unroll
            for (int dd = 0; dd < 5; ++dd) {
                float s = ldv(fr + j0[dd]) * (1.f - wq[dd]) + ldv(fr + j1[dd]) * wq[dd];
                cost[g * 5 + dd] = fmaf(fl, s, cost[g * 5 + dd]);
            }
        }
    }

    float sxv = ldv(sx_ + pix);
    float syv = ldv(sy_ + pix);
    float cfv = ldv(conf_ + pix);
    cbase[(size_t)128 * HW_] = f2b(d0);
    cbase[(size_t)129 * HW_] = f2b(sxv);
    cbase[(size_t)130 * HW_] = f2b(syv);
    cbase[(size_t)131 * HW_] = f2b(cfv);
    dscf[pix]             = d0;
    dscf[NPIX + pix]      = sxv;
    dscf[2 * NPIX + pix]  = syv;
    dscf[3 * NPIX + pix]  = cfv;
#pragma unroll
    for (int k = 0; k < 40; ++k)
        cbase[(size_t)(132 + k) * HW_] = f2b(cost[k] * 0.125f);    // / CG
}

// --------------------------------------------------------------- GRU conv ----
// MODE 0: out0 = sigmoid(conv + bias)              (z and r), bf16
// MODE 1: h_new = (1-z)*feat + z*tanh(conv + bias) -> hnewb (bf16 ws) and
//         d_out slot 3 in flag-selected dtype.
template<int MODE>
__global__ __launch_bounds__(256) void conv_gru(
    const bf16* __restrict__ srcA,      // [B][64][H][W] (featb or r*featb)
    const bf16* __restrict__ ctx,       // [B][172][H][W]
    const float* __restrict__ wt,       // [236][64*9]
    const bf16* __restrict__ bias,      // [64]
    bf16* __restrict__ out0,
    const bf16* __restrict__ z_in,
    const bf16* __restrict__ featb,
    bf16* __restrict__ hnewb,
    void* __restrict__ out_base,        // d_out
    const int* __restrict__ flag)
{
    const int x  = threadIdx.x;
    int blk = blockIdx.x;
    const int half = blk & 1; blk >>= 1;
    const int y = blk & (H_ - 1);
    const int b = blk >> 7;
    const int cob = half * 32;

    int   offs[9];
    float msk[9];
#pragma unroll
    for (int ky = 0; ky < 3; ++ky)
#pragma unroll
        for (int kx = 0; kx < 3; ++kx) {
            int yy = y + ky - 1, xx = x + kx - 1;
            bool valid = (yy >= 0) & (yy < H_) & (xx >= 0) & (xx < W_);
            int yc = min(max(yy, 0), H_ - 1);
            int xc = min(max(xx, 0), W_ - 1);
            offs[ky * 3 + kx] = yc * W_ + xc;
            msk[ky * 3 + kx] = valid ? 1.f : 0.f;
        }

    float acc[32];
#pragma unroll
    for (int i = 0; i < 32; ++i) acc[i] = 0.f;

    const bf16* pa = srcA + (size_t)b * 64 * HW_;
    const float* w = wt + cob * 9;
    for (int ci = 0; ci < 64; ++ci) {
        float v[9];
#pragma unroll
        for (int k = 0; k < 9; ++k) v[k] = msk[k] * b2f(pa[offs[k]]);
#pragma unroll
        for (int co = 0; co < 32; ++co) {
            float a = acc[co];
#pragma unroll
            for (int k = 0; k < 9; ++k) a = fmaf(w[co * 9 + k], v[k], a);
            acc[co] = a;
        }
        pa += HW_;
        w  += 576;
    }
    const bf16* pc = ctx + (size_t)b * CTXC * HW_;
    for (int ci = 0; ci < CTXC; ++ci) {
        float v[9];
#pragma unroll
        for (int k = 0; k < 9; ++k) v[k] = msk[k] * b2f(pc[offs[k]]);
#pragma unroll
        for (int co = 0; co < 32; ++co) {
            float a = acc[co];
#pragma unroll
            for (int k = 0; k < 9; ++k) a = fmaf(w[co * 9 + k], v[k], a);
            acc[co] = a;
        }
        pc += HW_;
        w  += 576;
    }

    const int pix = y * W_ + x;
    if (MODE == 0) {
#pragma unroll
        for (int co = 0; co < 32; ++co) {
            float s = acc[co] + b2f(bias[cob + co]);
            out0[(size_t)(b * 64 + cob + co) * HW_ + pix] = f2b(1.f / (1.f + expf(-s)));
        }
    } else {
        const int fl = *flag;
        float* outf = (float*)out_base + 393216;
        bf16*  outb = (bf16*)out_base + 393216;
#pragma unroll
        for (int co = 0; co < 32; ++co) {
            float q = tanhf(acc[co] + b2f(bias[cob + co]));
            size_t idx = (size_t)(b * 64 + cob + co) * HW_ + pix;
            float zv = b2f(z_in[idx]);
            float fv = b2f(featb[idx]);
            float hv = (1.f - zv) * fv + zv * q;
            hnewb[idx] = f2b(hv);
            if (fl) outf[idx] = hv;
            else    outb[idx] = f2b(hv);
        }
    }
}

// ------------------------------------------------------------- trunk conv ----
template<int CIN, int COUT, int COPB>
__global__ __launch_bounds__(256) void conv_trunk(
    const bf16* __restrict__ src, const float* __restrict__ wt,
    bf16* __restrict__ out)
{
    const int x  = threadIdx.x;
    int blk = blockIdx.x;
    const int nsplit = COUT / COPB;
    const int part = blk % nsplit; blk /= nsplit;
    const int y = blk & (H_ - 1);
    const int b = blk >> 7;
    const int cob = part * COPB;

    int   offs[9];
    float msk[9];
#pragma unroll
    for (int ky = 0; ky < 3; ++ky)
#pragma unroll
        for (int kx = 0; kx < 3; ++kx) {
            int yy = y + ky - 1, xx = x + kx - 1;
            bool valid = (yy >= 0) & (yy < H_) & (xx >= 0) & (xx < W_);
            int yc = min(max(yy, 0), H_ - 1);
            int xc = min(max(xx, 0), W_ - 1);
            offs[ky * 3 + kx] = yc * W_ + xc;
            msk[ky * 3 + kx] = valid ? 1.f : 0.f;
        }

    float acc[COPB];
#pragma unroll
    for (int i = 0; i < COPB; ++i) acc[i] = 0.f;

    const bf16* p = src + (size_t)b * CIN * HW_;
    const float* w = wt + cob * 9;
    for (int ci = 0; ci < CIN; ++ci) {
        float v[9];
#pragma unroll
        for (int k = 0; k < 9; ++k) v[k] = msk[k] * b2f(p[offs[k]]);
#pragma unroll
        for (int co = 0; co < COPB; ++co) {
            float a = acc[co];
#pragma unroll
            for (int k = 0; k < 9; ++k) a = fmaf(w[co * 9 + k], v[k], a);
            acc[co] = a;
        }
        p += HW_;
        w += COUT * 9;
    }
    const int pix = y * W_ + x;
#pragma unroll
    for (int co = 0; co < COPB; ++co)
        out[(size_t)(b * COUT + cob + co) * HW_ + pix] = f2b(acc[co]);
}

// -------------------------------------------------------------- groupnorm ----
__global__ __launch_bounds__(256) void gn_reduce(const bf16* __restrict__ x,
                                                 float* __restrict__ part)
{
    const int gp = blockIdx.x >> 3;     // (b*8+g), 0..31
    const int pt = blockIdx.x & 7;
    const int CHUNK = 6 * HW_ / 8;      // 24576
    const bf16* base = x + (size_t)gp * 6 * HW_ + (size_t)pt * CHUNK;
    float s = 0.f, ss = 0.f;
    for (int i = threadIdx.x; i < CHUNK; i += 256) {
        float v = b2f(base[i]);
        s += v;
        ss = fmaf(v, v, ss);
    }
#pragma unroll
    for (int o = 32; o > 0; o >>= 1) {
        s  += __shfl_down(s, o, 64);
        ss += __shfl_down(ss, o, 64);
    }
    __shared__ float sm[8];
    int wid = threadIdx.x >> 6;
    if ((threadIdx.x & 63) == 0) { sm[wid * 2] = s; sm[wid * 2 + 1] = ss; }
    __syncthreads();
    if (threadIdx.x == 0) {
        float S = 0.f, SS = 0.f;
        for (int i = 0; i < 4; ++i) { S += sm[i * 2]; SS += sm[i * 2 + 1]; }
        part[(gp * 8 + pt) * 2]     = S;
        part[(gp * 8 + pt) * 2 + 1] = SS;
    }
}

__global__ void gn_finalize(const float* __restrict__ part, float* __restrict__ stats)
{
    int gp = threadIdx.x;
    if (gp >= 32) return;
    float S = 0.f, SS = 0.f;
    for (int i = 0; i < 8; ++i) {
        S  += part[(gp * 8 + i) * 2];
        SS += part[(gp * 8 + i) * 2 + 1];
    }
    const float N = 6.f * HW_;
    float m  = S / N;
    float var = SS / N - m * m;
    var = fmaxf(var, 0.f);
    stats[gp * 2]     = m;
    stats[gp * 2 + 1] = rsqrtf(var + 1e-5f);
}

__global__ __launch_bounds__(256) void gn_apply(bf16* __restrict__ x,
                                                const float* __restrict__ stats,
                                                const bf16* __restrict__ scbi)
{
    int i  = blockIdx.x * 256 + threadIdx.x;   // < B*48*HW
    int bc = i >> 15;                          // b*48 + c
    int c  = bc % 48;
    int gp = bc / 6;                           // b*8 + c/6
    float m = stats[gp * 2], r = stats[gp * 2 + 1];
    float v = (b2f(x[i]) - m) * r * b2f(scbi[c]) + b2f(scbi[48 + c]);
    x[i] = f2b(v / (1.f + expf(-v)));          // silu
}

// ------------------------------------------------------------- elementwise ---
__global__ __launch_bounds__(256) void rfeat_k(bf16* __restrict__ r,
                                               const bf16* __restrict__ featb)
{
    int i = blockIdx.x * 256 + threadIdx.x;
    r[i] = f2b(b2f(r[i]) * b2f(featb[i]));
}

// ------------------------------------------------------------------ heads ----
__global__ __launch_bounds__(256) void heads_k(
    const bf16* __restrict__ t2,       // [B][48][HW]
    const bf16* __restrict__ sp,       // sparams
    const float* __restrict__ dscf,    // exact f32 d/sx/sy/conf planes
    void* __restrict__ out_base,
    const int* __restrict__ flag)
{
    int pix = blockIdx.x * 256 + threadIdx.x;  // 0..131071
    int b   = pix >> 15;
    int hw  = pix & (HW_ - 1);
    const bf16* t = t2 + (size_t)b * 48 * HW_ + hw;
    float ad = 0.f, ax = 0.f, ay = 0.f, ac = 0.f;
#pragma unroll
    for (int c = 0; c < 48; ++c) {
        float v = b2f(t[(size_t)c * HW_]);
        ad = fmaf(v, b2f(sp[384 + c]), ad);
        ax = fmaf(v, b2f(sp[432 + c]), ax);
        ay = fmaf(v, b2f(sp[480 + c]), ay);
        ac = fmaf(v, b2f(sp[528 + c]), ac);
    }
    float dv  = dscf[pix];
    float sxv = dscf[NPIX + pix];
    float syv = dscf[2 * NPIX + pix];
    float cfv = dscf[3 * NPIX + pix];

    float dval = ad + b2f(sp[576]) + dv;
    float spv = fmaxf(dval, 0.f) + log1pf(expf(-fabsf(dval)));   // stable softplus
    float sxo = sxv + 0.1f * (ax + b2f(sp[577]));
    float syo = syv + 0.1f * (ay + b2f(sp[578]));
    float cvv = 1.f / (1.f + expf(-(ac + b2f(sp[579]) + 2.f * cfv - 1.f)));

    if (*flag) {
        float* of = (float*)out_base;
        of[pix]              = spv;
        of[NPIX + pix]       = sxo;
        of[2 * NPIX + pix]   = syo;
        of[8781824 + pix]    = cvv;
    } else {
        bf16* ob = (bf16*)out_base;
        ob[pix]              = f2b(spv);
        ob[NPIX + pix]       = f2b(sxo);
        ob[2 * NPIX + pix]   = f2b(syo);
        ob[8781824 + pix]    = f2b(cvv);
    }
}

// ------------------------------------------------------------------ launch ---
extern "C" void kernel_launch(void* const* d_in, const int* in_sizes, int n_in,
                              void* d_out, int out_size, void* d_ws, size_t ws_size,
                              hipStream_t stream)
{
    char* ws = (char*)d_ws;
    size_t off = 0;
    bf16*  ctx   = (bf16*)(ws + off); off += (size_t)B_ * CTXC * HW_ * 2;  // 45.1 MB
    bf16*  featb = (bf16*)(ws + off); off += (size_t)B_ * 64 * HW_ * 2;    // 16.8 MB
    bf16*  zslot = (bf16*)(ws + off); off += (size_t)B_ * 64 * HW_ * 2;    // z, then t1
    bf16*  rslot = (bf16*)(ws + off); off += (size_t)B_ * 64 * HW_ * 2;    // r/rfeat, then t2
    bf16*  hnewb = (bf16*)(ws + off); off += (size_t)B_ * 64 * HW_ * 2;    // h_new (ws copy)
    float* dscf  = (float*)(ws + off); off += (size_t)4 * NPIX * 4;        // 2.1 MB
    float* wtz   = (float*)(ws + off); off += GRUIN * 64 * 9 * 4;
    float* wtr   = (float*)(ws + off); off += GRUIN * 64 * 9 * 4;
    float* wtq   = (float*)(ws + off); off += GRUIN * 64 * 9 * 4;
    float* wt1   = (float*)(ws + off); off += 64 * 48 * 9 * 4;
    float* wt2   = (float*)(ws + off); off += 48 * 48 * 9 * 4;
    bf16*  sprm  = (bf16*)(ws + off); off += 1280;
    float* gpart = (float*)(ws + off); off += 512 * 4;
    float* gstat = (float*)(ws + off); off += 64 * 4;
    int*   flag  = (int*)(ws + off);   off += 256;
    // total ~116 MB

    detect_k<<<1, 64, 0, stream>>>((const unsigned int*)d_in[4], flag);

    // ---- dual-dtype staging (mismatched variant early-outs on flag) ----
    {
        const int gw = (GRUIN * 64 * 9 + 255) / 256;
        wcvt<bf16 ><<<gw, 256, 0, stream>>>(flag, (const bf16*)d_in[7],  wtz, 64, GRUIN);
        wcvt<float><<<gw, 256, 0, stream>>>(flag, (const float*)d_in[7], wtz, 64, GRUIN);
        wcvt<bf16 ><<<gw, 256, 0, stream>>>(flag, (const bf16*)d_in[9],  wtr, 64, GRUIN);
        wcvt<float><<<gw, 256, 0, stream>>>(flag, (const float*)d_in[9], wtr, 64, GRUIN);
        wcvt<bf16 ><<<gw, 256, 0, stream>>>(flag, (const bf16*)d_in[11],  wtq, 64, GRUIN);
        wcvt<float><<<gw, 256, 0, stream>>>(flag, (const float*)d_in[11], wtq, 64, GRUIN);
        const int g1 = (48 * 64 * 9 + 255) / 256;
        wcvt<bf16 ><<<g1, 256, 0, stream>>>(flag, (const bf16*)d_in[13],  wt1, 48, 64);
        wcvt<float><<<g1, 256, 0, stream>>>(flag, (const float*)d_in[13], wt1, 48, 64);
        const int g2 = (48 * 48 * 9 + 255) / 256;
        wcvt<bf16 ><<<g2, 256, 0, stream>>>(flag, (const bf16*)d_in[16],  wt2, 48, 48);
        wcvt<float><<<g2, 256, 0, stream>>>(flag, (const float*)d_in[16], wt2, 48, 48);
    }
    cvt_small<bf16><<<3, 256, 0, stream>>>(flag,
        (const bf16*)d_in[8], (const bf16*)d_in[10], (const bf16*)d_in[12],
        (const bf16*)d_in[14], (const bf16*)d_in[15], (const bf16*)d_in[17], (const bf16*)d_in[18],
        (const bf16*)d_in[19], (const bf16*)d_in[21], (const bf16*)d_in[23], (const bf16*)d_in[25],
        (const bf16*)d_in[20], (const bf16*)d_in[22], (const bf16*)d_in[24], (const bf16*)d_in[26],
        sprm);
    cvt_small<float><<<3, 256, 0, stream>>>(flag,
        (const float*)d_in[8], (const float*)d_in[10], (const float*)d_in[12],
        (const float*)d_in[14], (const float*)d_in[15], (const float*)d_in[17], (const float*)d_in[18],
        (const float*)d_in[19], (const float*)d_in[21], (const float*)d_in[23], (const float*)d_in[25],
        (const float*)d_in[20], (const float*)d_in[22], (const float*)d_in[24], (const float*)d_in[26],
        sprm);

    const int nf = B_ * 64 * HW_;
    cvt_big<bf16 ><<<nf / 256, 256, 0, stream>>>(flag, (const bf16*)d_in[4],  featb, nf);
    cvt_big<float><<<nf / 256, 256, 0, stream>>>(flag, (const float*)d_in[4], featb, nf);

    build_ctx<bf16 ><<<B_ * H_, 256, 0, stream>>>(flag,
        (const bf16*)d_in[0], (const bf16*)d_in[1], (const bf16*)d_in[2],
        (const bf16*)d_in[3], (const bf16*)d_in[5], (const bf16*)d_in[6], ctx, dscf);
    build_ctx<float><<<B_ * H_, 256, 0, stream>>>(flag,
        (const float*)d_in[0], (const float*)d_in[1], (const float*)d_in[2],
        (const float*)d_in[3], (const float*)d_in[5], (const float*)d_in[6], ctx, dscf);

    // ---- core pipeline (all bf16 staged) ----
    conv_gru<0><<<B_ * H_ * 2, 256, 0, stream>>>(featb, ctx, wtz, sprm + 0, zslot,
                                                 nullptr, nullptr, nullptr, nullptr, flag);
    conv_gru<0><<<B_ * H_ * 2, 256, 0, stream>>>(featb, ctx, wtr, sprm + 64, rslot,
                                                 nullptr, nullptr, nullptr, nullptr, flag);
    rfeat_k<<<nf / 256, 256, 0, stream>>>(rslot, featb);

    conv_gru<1><<<B_ * H_ * 2, 256, 0, stream>>>(rslot, ctx, wtq, sprm + 128,
                                                 nullptr, zslot, featb, hnewb, d_out, flag);

    // trunk 1: h_new (bf16 ws) -> t1 (zslot)
    conv_trunk<64, 48, 24><<<B_ * H_ * 2, 256, 0, stream>>>(hnewb, wt1, zslot);
    gn_reduce<<<256, 256, 0, stream>>>(zslot, gpart);
    gn_finalize<<<1, 32, 0, stream>>>(gpart, gstat);
    gn_apply<<<B_ * 48 * HW_ / 256, 256, 0, stream>>>(zslot, gstat, sprm + 192);

    // trunk 2: t1 -> t2 (rslot)
    conv_trunk<48, 48, 24><<<B_ * H_ * 2, 256, 0, stream>>>(zslot, wt2, rslot);
    gn_reduce<<<256, 256, 0, stream>>>(rslot, gpart);
    gn_finalize<<<1, 32, 0, stream>>>(gpart, gstat);
    gn_apply<<<B_ * 48 * HW_ / 256, 256, 0, stream>>>(rslot, gstat, sprm + 288);

    heads_k<<<B_ * H_, 256, 0, stream>>>(rslot, sprm, dscf, d_out, flag);
}

// Round 4
// 951.755 us; speedup vs baseline: 3.2177x; 3.2177x over previous
//
#include <hip/hip_runtime.h>
#include <hip/hip_bf16.h>
#include <math.h>
#include <type_traits>

typedef __hip_bfloat16 bf16;
typedef __attribute__((ext_vector_type(8))) short bf16x8;
typedef __attribute__((ext_vector_type(4))) float f32x4;

#define B_    4
#define H_    128
#define W_    256
#define HW_   32768          // H_*W_
#define CTXC  172
#define NPIX  131072         // B_*HW_
#define RW    258            // W_+2 (halo row width)
#define RH    130            // H_+2
#define IPX   33540          // RW*RH pixels per image (halo incl.)

__device__ __forceinline__ float b2f(bf16 v) { return __bfloat162float(v); }
__device__ __forceinline__ bf16  f2b(float v){ return __float2bfloat16(v); }
__device__ __forceinline__ unsigned short f2bu(float v){ bf16 h = f2b(v); return *(unsigned short*)&h; }
__device__ __forceinline__ float ldv(const float* p){ return *p; }
__device__ __forceinline__ float ldv(const bf16* p) { return b2f(*p); }

// ------------------------------------------------------------- dtype detect --
__global__ void detect_k(const unsigned int* __restrict__ feat_raw,
                         int* __restrict__ flag)
{
    if (threadIdx.x != 0 || blockIdx.x != 0) return;
    int hits = 0;
    for (int i = 0; i < 64; ++i) {
        unsigned int w = feat_raw[i];
        unsigned int e = (w >> 7) & 0xFFu;
        hits += (e >= 0xC0u) ? 1 : 0;
    }
    *flag = (hits > 0) ? 1 : 0;
}

template<typename IT>
__device__ __forceinline__ bool gate_skip(const int* flag)
{
    constexpr bool isf = std::is_same<IT, float>::value;
    return (*flag != 0) != isf;
}

// ---------------------------------------------------- weight fragment shuffle
// GRU conv weights [64][236][3][3] -> B-fragment order for implicit GEMM.
// K-order per tap: k 0..191 = ctx channel k (orig ci=64+k; k>=172 zero pad),
//                  k 192..255 = feat channel k-192 (orig ci=k-192).
// dst idx i = (((t*8 + s)*4 + u)*64 + lane)*8 + j ; value = W[n=16u+(lane&15)]
//             [k = 32s + (lane>>4)*8 + j][tap t]
template<typename IT>
__global__ __launch_bounds__(256) void wfrag_gru(const int* __restrict__ flag,
                                                 const IT* __restrict__ src,
                                                 bf16* __restrict__ dst)
{
    if (gate_skip<IT>(flag)) return;
    int i = blockIdx.x * 256 + threadIdx.x;
    if (i >= 9*8*4*64*8) return;
    int j    = i & 7;
    int lane = (i >> 3) & 63;
    int u    = (i >> 9) & 3;
    int s    = (i >> 11) & 7;
    int t    = i >> 14;
    int klocal = ((lane >> 4) << 3) + j;
    int co = u * 16 + (lane & 15);
    float v = 0.f;
    if (s < 6) {
        int k = s * 32 + klocal;
        if (k < CTXC) v = ldv(src + ((size_t)co * 236 + 64 + k) * 9 + t);
    } else {
        int kf = (s - 6) * 32 + klocal;
        v = ldv(src + ((size_t)co * 236 + kf) * 9 + t);
    }
    dst[i] = f2b(v);
}

// trunk weights [CO=48][CIN][3][3] -> frag order, Kpad=64 (2 ksteps), NT=3
template<typename IT>
__global__ __launch_bounds__(256) void wfrag_trunk(const int* __restrict__ flag,
                                                   const IT* __restrict__ src,
                                                   bf16* __restrict__ dst, int CIN)
{
    if (gate_skip<IT>(flag)) return;
    int i = blockIdx.x * 256 + threadIdx.x;
    if (i >= 9*2*3*64*8) return;
    int j    = i & 7;
    int lane = (i >> 3) & 63;
    int rest = i >> 9;
    int u = rest % 3; rest /= 3;
    int s = rest & 1;
    int t = rest >> 1;
    int k = s * 32 + ((lane >> 4) << 3) + j;
    int co = u * 16 + (lane & 15);
    float v = (k < CIN) ? ldv(src + ((size_t)co * CIN + k) * 9 + t) : 0.f;
    dst[i] = f2b(v);
}

// small params -> sparams layout (same as R3):
// 0:zb 64:rb 128:qb 192:g1s 240:g1b 288:g2s 336:g2b 384:wd 432:wx 480:wy 528:wc
// 576:bd 577:bx 578:by 579:bc
template<typename IT>
__global__ void cvt_small(const int* __restrict__ flag,
    const IT* zb, const IT* rb, const IT* qb,
    const IT* g1s, const IT* g1b, const IT* g2s, const IT* g2b,
    const IT* wd, const IT* wx, const IT* wy, const IT* wc,
    const IT* bd, const IT* bx, const IT* by, const IT* bc,
    bf16* __restrict__ dst)
{
    if (gate_skip<IT>(flag)) return;
    int i = blockIdx.x * 256 + threadIdx.x;
    if (i >= 580) return;
    const IT* src; int off;
    if      (i < 64)  { src = zb;  off = i; }
    else if (i < 128) { src = rb;  off = i - 64; }
    else if (i < 192) { src = qb;  off = i - 128; }
    else if (i < 240) { src = g1s; off = i - 192; }
    else if (i < 288) { src = g1b; off = i - 240; }
    else if (i < 336) { src = g2s; off = i - 288; }
    else if (i < 384) { src = g2b; off = i - 336; }
    else if (i < 432) { src = wd;  off = i - 384; }
    else if (i < 480) { src = wx;  off = i - 432; }
    else if (i < 528) { src = wy;  off = i - 480; }
    else if (i < 576) { src = wc;  off = i - 528; }
    else if (i == 576){ src = bd;  off = 0; }
    else if (i == 577){ src = bx;  off = 0; }
    else if (i == 578){ src = by;  off = 0; }
    else              { src = bc;  off = 0; }
    dst[i] = f2b(ldv(src + off));
}

// ------------------------------------------------------------------- ctx -----
// planar ctx channels: [fL 0..63][fR_w 64..127][d 128][sx 129][sy 130][conf 131][cost 132..171]
template<typename IT>
__global__ __launch_bounds__(256) void build_ctx(
    const int* __restrict__ flag,
    const IT* __restrict__ d_, const IT* __restrict__ sx_,
    const IT* __restrict__ sy_, const IT* __restrict__ conf_,
    const IT* __restrict__ fL, const IT* __restrict__ fR,
    bf16* __restrict__ ctx, float* __restrict__ dscf)
{
    if (gate_skip<IT>(flag)) return;
    const int x   = threadIdx.x;
    const int blk = blockIdx.x;
    const int y   = blk & (H_ - 1);
    const int b   = blk >> 7;
    const int pix = (b << 15) | (y << 8) | x;

    const float d0 = ldv(d_ + pix);

    float xw = fminf(fmaxf((float)x - d0, 0.f), (float)(W_ - 1));
    float x0 = floorf(xw);
    float w1 = xw - x0;
    int i0 = (int)x0;
    int i1 = min(i0 + 1, W_ - 1);

    int   j0[5], j1[5];
    float wq[5];
#pragma unroll
    for (int dd = 0; dd < 5; ++dd) {
        float cd = fminf(fmaxf((float)x - d0 - (float)(dd - 2), 0.f), (float)(W_ - 1));
        float c0 = floorf(cd);
        wq[dd] = cd - c0;
        j0[dd] = (int)c0;
        j1[dd] = min(j0[dd] + 1, W_ - 1);
    }

    float cost[40];
#pragma unroll
    for (int k = 0; k < 40; ++k) cost[k] = 0.f;

    const IT* fLrow = fL + (size_t)b * 64 * HW_ + y * W_;
    const IT* fRrow = fR + (size_t)b * 64 * HW_ + y * W_;
    bf16* cbase = ctx + (size_t)b * CTXC * HW_ + y * W_ + x;

#pragma unroll
    for (int g = 0; g < 8; ++g) {
#pragma unroll
        for (int cc = 0; cc < 8; ++cc) {
            const int c = g * 8 + cc;
            const IT* fr = fRrow + (size_t)c * HW_;
            float fl = ldv(fLrow + (size_t)c * HW_ + x);
            cbase[(size_t)c * HW_] = f2b(fl);
            float fw = ldv(fr + i0) * (1.f - w1) + ldv(fr + i1) * w1;
            cbase[(size_t)(64 + c) * HW_] = f2b(fw);
#pragma unroll
            for (int dd = 0; dd < 5; ++dd) {
                float s = ldv(fr + j0[dd]) * (1.f - wq[dd]) + ldv(fr + j1[dd]) * wq[dd];
                cost[g * 5 + dd] = fmaf(fl, s, cost[g * 5 + dd]);
            }
        }
    }

    float sxv = ldv(sx_ + pix);
    float syv = ldv(sy_ + pix);
    float cfv = ldv(conf_ + pix);
    cbase[(size_t)128 * HW_] = f2b(d0);
    cbase[(size_t)129 * HW_] = f2b(sxv);
    cbase[(size_t)130 * HW_] = f2b(syv);
    cbase[(size_t)131 * HW_] = f2b(cfv);
    dscf[pix]             = d0;
    dscf[NPIX + pix]      = sxv;
    dscf[2 * NPIX + pix]  = syv;
    dscf[3 * NPIX + pix]  = cfv;
#pragma unroll
    for (int k = 0; k < 40; ++k)
        cbase[(size_t)(132 + k) * HW_] = f2b(cost[k] * 0.125f);
}

// --------------------------------------------- planar -> NHWC-halo transposes
// ctx planar [b][172][HW] -> xctx [b][130][258][192] (ch>=172 zero), interior only
__global__ __launch_bounds__(256) void to_nhwc_ctx(const bf16* __restrict__ src,
                                                   bf16* __restrict__ dst)
{
    __shared__ bf16 lds[128 * 210];
    int blk = blockIdx.x;               // B*H*2
    int half = blk & 1; blk >>= 1;
    int y = blk & (H_ - 1);
    int b = blk >> 7;
    int x0 = half * 128;
    int t = threadIdx.x;
    int p = t & 127, c0 = t >> 7;
    const bf16* sp = src + (size_t)b * CTXC * HW_ + y * W_ + x0 + p;
    for (int c = c0; c < CTXC; c += 2)
        lds[p * 210 + c] = sp[(size_t)c * HW_];
    for (int idx = t; idx < 128 * 10; idx += 256) {
        int pp = idx / 10, jj = idx % 10;
        *(unsigned int*)&lds[pp * 210 + 172 + 2 * jj] = 0u;
    }
    __syncthreads();
    unsigned int* dw = (unsigned int*)(dst + ((size_t)(b * RH + y + 1) * RW + 1 + x0) * 192);
    for (int idx = t; idx < 128 * 96; idx += 256) {
        int pp = idx / 96, jj = idx % 96;
        dw[pp * 96 + jj] = *(unsigned int*)&lds[pp * 210 + 2 * jj];
    }
}

// feat planar (input dtype) [b][64][HW] -> xfeat [b][130][258][64], interior only
template<typename IT>
__global__ __launch_bounds__(256) void to_nhwc_in(const int* __restrict__ flag,
                                                  const IT* __restrict__ src,
                                                  bf16* __restrict__ dst)
{
    if (gate_skip<IT>(flag)) return;
    __shared__ bf16 lds[128 * 66];
    int blk = blockIdx.x;
    int half = blk & 1; blk >>= 1;
    int y = blk & (H_ - 1);
    int b = blk >> 7;
    int x0 = half * 128;
    int t = threadIdx.x;
    int p = t & 127, c0 = t >> 7;
    const IT* sp = src + (size_t)b * 64 * HW_ + y * W_ + x0 + p;
    for (int c = c0; c < 64; c += 2)
        lds[p * 66 + c] = f2b(ldv(sp + (size_t)c * HW_));
    __syncthreads();
    unsigned int* dw = (unsigned int*)(dst + ((size_t)(b * RH + y + 1) * RW + 1 + x0) * 64);
    for (int idx = t; idx < 128 * 32; idx += 256) {
        int pp = idx >> 5, jj = idx & 31;
        dw[pp * 32 + jj] = *(unsigned int*)&lds[pp * 66 + 2 * jj];
    }
}

// ----------------------------------------------------------------- zeroing ---
__global__ __launch_bounds__(256) void zero_halo(bf16* __restrict__ buf, int CP)
{
    int yy = blockIdx.x % RH;
    int b  = blockIdx.x / RH;
    for (int x = threadIdx.x; x < RW; x += 256) {
        bool h = (yy == 0) | (yy == RH - 1) | (x == 0) | (x == RW - 1);
        if (!h) continue;
        bf16* p = buf + ((size_t)(b * RH + yy) * RW + x) * CP;
        uint4 z = {0u, 0u, 0u, 0u};
        for (int c = 0; c < CP; c += 8)
            *(uint4*)(p + c) = z;
    }
}

__global__ __launch_bounds__(256) void zero_full(bf16* __restrict__ buf, int n16)
{
    int i = blockIdx.x * 256 + threadIdx.x;
    if (i >= n16) return;
    uint4 z = {0u, 0u, 0u, 0u};
    *(uint4*)(buf + (size_t)i * 8) = z;
}

// ------------------------------------------------------- MFMA implicit conv --
// GEMM over taps: K per tap = KSA*32 (srcA, stride CPA) + KSB*32 (srcB, stride 64).
// Block = one image row (4 waves x 64 px); wave: 4 M-tiles x NT N-tiles.
// MODE 0: sigmoid(acc+bias) -> outn (NHWC, CPO=64)
// MODE 1: GRU combine -> outn (xt NHWC 64) + d_out slot3 planar (flag dtype)
// MODE 2: plain -> outn (NHWC, CPO)
template<int KSA, int KSB, int NT, int MODE>
__global__ __launch_bounds__(256) void conv_mfma(
    const bf16* __restrict__ srcA, const bf16* __restrict__ srcB,
    const bf16* __restrict__ wfrag, const bf16* __restrict__ bias,
    bf16* __restrict__ outn,
    const bf16* __restrict__ xz, const bf16* __restrict__ xf,
    void* __restrict__ dout, const int* __restrict__ flag,
    int CPA, int CPO)
{
    const int tid  = threadIdx.x;
    const int lane = tid & 63;
    const int wv   = tid >> 6;
    const int y    = blockIdx.x & (H_ - 1);
    const int b    = blockIdx.x >> 7;
    const int m    = lane & 15;
    const int quad = lane >> 4;
    const int kA   = quad << 3;
    constexpr int KST = KSA + KSB;

    f32x4 acc[4][NT];
#pragma unroll
    for (int mt = 0; mt < 4; ++mt)
#pragma unroll
        for (int u = 0; u < NT; ++u)
            acc[mt][u] = (f32x4){0.f, 0.f, 0.f, 0.f};

    int pxA[4];
#pragma unroll
    for (int mt = 0; mt < 4; ++mt) pxA[mt] = wv * 64 + mt * 16 + m;

    const bf16* baseA = srcA + (size_t)(b * RH + y) * RW * CPA;
    const bf16* baseB = (KSB > 0) ? srcB + (size_t)(b * RH + y) * RW * 64 : nullptr;

    for (int t = 0; t < 9; ++t) {
        const int dyp = t / 3, dxp = t % 3;
        const bf16* rA = baseA + ((size_t)dyp * RW + dxp) * CPA;
#pragma unroll
        for (int s = 0; s < KSA; ++s) {
            bf16x8 a[4];
#pragma unroll
            for (int mt = 0; mt < 4; ++mt)
                a[mt] = *(const bf16x8*)(rA + (size_t)pxA[mt] * CPA + s * 32 + kA);
#pragma unroll
            for (int u = 0; u < NT; ++u) {
                bf16x8 bw = *(const bf16x8*)(wfrag +
                    ((size_t)(((t * KST + s) * NT + u) * 64 + lane) << 3));
#pragma unroll
                for (int mt = 0; mt < 4; ++mt)
                    acc[mt][u] = __builtin_amdgcn_mfma_f32_16x16x32_bf16(
                        a[mt], bw, acc[mt][u], 0, 0, 0);
            }
        }
        if (KSB > 0) {
            const bf16* rB = baseB + ((size_t)dyp * RW + dxp) * 64;
#pragma unroll
            for (int s = 0; s < KSB; ++s) {
                bf16x8 a[4];
#pragma unroll
                for (int mt = 0; mt < 4; ++mt)
                    a[mt] = *(const bf16x8*)(rB + (size_t)pxA[mt] * 64 + s * 32 + kA);
#pragma unroll
                for (int u = 0; u < NT; ++u) {
                    bf16x8 bw = *(const bf16x8*)(wfrag +
                        ((size_t)(((t * KST + KSA + s) * NT + u) * 64 + lane) << 3));
#pragma unroll
                    for (int mt = 0; mt < 4; ++mt)
                        acc[mt][u] = __builtin_amdgcn_mfma_f32_16x16x32_bf16(
                            a[mt], bw, acc[mt][u], 0, 0, 0);
                }
            }
        }
    }

    const size_t rowo = (size_t)(b * RH + y + 1) * RW + 1;
#pragma unroll
    for (int mt = 0; mt < 4; ++mt) {
        const int px0 = wv * 64 + mt * 16 + quad * 4;
#pragma unroll
        for (int u = 0; u < NT; ++u) {
            const int n = u * 16 + m;
            if (MODE == 0) {
                float bn = b2f(bias[n]);
#pragma unroll
                for (int r = 0; r < 4; ++r) {
                    float v = acc[mt][u][r] + bn;
                    outn[(rowo + px0 + r) * 64 + n] = f2b(1.f / (1.f + expf(-v)));
                }
            } else if (MODE == 2) {
#pragma unroll
                for (int r = 0; r < 4; ++r)
                    outn[(rowo + px0 + r) * CPO + n] = f2b(acc[mt][u][r]);
            } else {
                float bn = b2f(bias[n]);
                float hv[4];
#pragma unroll
                for (int r = 0; r < 4; ++r) {
                    float q = tanhf(acc[mt][u][r] + bn);
                    size_t ai = (rowo + px0 + r) * 64 + n;
                    float zv = b2f(xz[ai]);
                    float fv = b2f(xf[ai]);
                    hv[r] = (1.f - zv) * fv + zv * q;
                    outn[ai] = f2b(hv[r]);
                }
                size_t pb = ((size_t)(b * 64 + n) << 15) + y * W_ + px0;
                if (*flag) {
                    float4 o; o.x = hv[0]; o.y = hv[1]; o.z = hv[2]; o.w = hv[3];
                    *(float4*)((float*)dout + 393216 + pb) = o;
                } else {
                    ushort4 o;
                    o.x = f2bu(hv[0]); o.y = f2bu(hv[1]);
                    o.z = f2bu(hv[2]); o.w = f2bu(hv[3]);
                    *(ushort4*)((bf16*)dout + 393216 + pb) = o;
                }
            }
        }
    }
}

// ------------------------------------------------------------- elementwise ---
// xr *= xfeat over full buffer (halo: xfeat=0 -> 0)
__global__ __launch_bounds__(256) void rfeat_nhwc(bf16* __restrict__ xr,
                                                  const bf16* __restrict__ xf, int n2)
{
    int i = blockIdx.x * 256 + threadIdx.x;
    if (i >= n2) return;
    unsigned int a = ((const unsigned int*)xr)[i];
    unsigned int f = ((const unsigned int*)xf)[i];
    bf16 a0, a1, f0, f1;
    *(unsigned short*)&a0 = a & 0xFFFFu;  *(unsigned short*)&a1 = a >> 16;
    *(unsigned short*)&f0 = f & 0xFFFFu;  *(unsigned short*)&f1 = f >> 16;
    unsigned int r = (unsigned int)f2bu(b2f(a0) * b2f(f0)) |
                     ((unsigned int)f2bu(b2f(a1) * b2f(f1)) << 16);
    ((unsigned int*)xr)[i] = r;
}

// -------------------------------------------------------------- groupnorm ----
__global__ __launch_bounds__(256) void gn_reduce_nhwc(const bf16* __restrict__ buf,
                                                      float* __restrict__ part, int CP)
{
    const int gp = blockIdx.x >> 3;     // b*8+g
    const int pt = blockIdx.x & 7;
    const int b = gp >> 3, g = gp & 7;
    const int lo = pt * 4193;
    const int hi = min(lo + 4193, IPX);
    const bf16* base = buf + (size_t)b * IPX * CP + g * 6;
    float s = 0.f, ss = 0.f;
    for (int px = lo + threadIdx.x; px < hi; px += 256) {
        const bf16* q = base + (size_t)px * CP;
#pragma unroll
        for (int c = 0; c < 6; ++c) {
            float v = b2f(q[c]);
            s += v;
            ss = fmaf(v, v, ss);
        }
    }
#pragma unroll
    for (int o = 32; o > 0; o >>= 1) {
        s  += __shfl_down(s, o, 64);
        ss += __shfl_down(ss, o, 64);
    }
    __shared__ float sm[8];
    int wid = threadIdx.x >> 6;
    if ((threadIdx.x & 63) == 0) { sm[wid * 2] = s; sm[wid * 2 + 1] = ss; }
    __syncthreads();
    if (threadIdx.x == 0) {
        float S = 0.f, SS = 0.f;
        for (int i = 0; i < 4; ++i) { S += sm[i * 2]; SS += sm[i * 2 + 1]; }
        part[(gp * 8 + pt) * 2]     = S;
        part[(gp * 8 + pt) * 2 + 1] = SS;
    }
}

__global__ void gn_finalize(const float* __restrict__ part, float* __restrict__ stats)
{
    int gp = threadIdx.x;
    if (gp >= 32) return;
    float S = 0.f, SS = 0.f;
    for (int i = 0; i < 8; ++i) {
        S  += part[(gp * 8 + i) * 2];
        SS += part[(gp * 8 + i) * 2 + 1];
    }
    const float N = 6.f * HW_;
    float mn  = S / N;
    float var = SS / N - mn * mn;
    var = fmaxf(var, 0.f);
    stats[gp * 2]     = mn;
    stats[gp * 2 + 1] = rsqrtf(var + 1e-5f);
}

// silu(gn(x)) in place, interior pixels, ch<48 only. CP = buffer stride.
__global__ __launch_bounds__(256) void gn_apply_nhwc(bf16* __restrict__ buf,
                                                     const float* __restrict__ stats,
                                                     const bf16* __restrict__ scbi,
                                                     int CP)
{
    const int y = blockIdx.x & (H_ - 1);
    const int b = blockIdx.x >> 7;
    bf16* base = buf + ((size_t)(b * RH + y + 1) * RW + 1) * CP;
    for (int j = threadIdx.x; j < W_ * 48; j += 256) {
        int px = j / 48;
        int c  = j - px * 48;
        int g  = c / 6;
        float mn = stats[(b * 8 + g) * 2], rr = stats[(b * 8 + g) * 2 + 1];
        size_t idx = (size_t)px * CP + c;
        float v = (b2f(base[idx]) - mn) * rr * b2f(scbi[c]) + b2f(scbi[48 + c]);
        base[idx] = f2b(v / (1.f + expf(-v)));
    }
}

// ------------------------------------------------------------------ heads ----
__global__ __launch_bounds__(256) void heads_k(
    const bf16* __restrict__ xt2,      // NHWC stride 48
    const bf16* __restrict__ sp,
    const float* __restrict__ dscf,
    void* __restrict__ out_base,
    const int* __restrict__ flag)
{
    const int x = threadIdx.x;
    const int y = blockIdx.x & (H_ - 1);
    const int b = blockIdx.x >> 7;
    const int pix = (b << 15) | (y << 8) | x;
    const bf16* t = xt2 + ((size_t)(b * RH + y + 1) * RW + 1 + x) * 48;
    float ad = 0.f, ax = 0.f, ay = 0.f, ac = 0.f;
#pragma unroll
    for (int c = 0; c < 48; ++c) {
        float v = b2f(t[c]);
        ad = fmaf(v, b2f(sp[384 + c]), ad);
        ax = fmaf(v, b2f(sp[432 + c]), ax);
        ay = fmaf(v, b2f(sp[480 + c]), ay);
        ac = fmaf(v, b2f(sp[528 + c]), ac);
    }
    float dv  = dscf[pix];
    float sxv = dscf[NPIX + pix];
    float syv = dscf[2 * NPIX + pix];
    float cfv = dscf[3 * NPIX + pix];

    float dval = ad + b2f(sp[576]) + dv;
    float spv = fmaxf(dval, 0.f) + log1pf(expf(-fabsf(dval)));
    float sxo = sxv + 0.1f * (ax + b2f(sp[577]));
    float syo = syv + 0.1f * (ay + b2f(sp[578]));
    float cvv = 1.f / (1.f + expf(-(ac + b2f(sp[579]) + 2.f * cfv - 1.f)));

    if (*flag) {
        float* of = (float*)out_base;
        of[pix]            = spv;
        of[NPIX + pix]     = sxo;
        of[2 * NPIX + pix] = syo;
        of[8781824 + pix]  = cvv;
    } else {
        bf16* ob = (bf16*)out_base;
        ob[pix]            = f2b(spv);
        ob[NPIX + pix]     = f2b(sxo);
        ob[2 * NPIX + pix] = f2b(syo);
        ob[8781824 + pix]  = f2b(cvv);
    }
}

// ------------------------------------------------------------------ launch ---
extern "C" void kernel_launch(void* const* d_in, const int* in_sizes, int n_in,
                              void* d_out, int out_size, void* d_ws, size_t ws_size,
                              hipStream_t stream)
{
    char* ws = (char*)d_ws;
    size_t off = 0;
    // region 0: planar ctx (45.1 MB); after to_nhwc_ctx reused as xz + xr
    bf16* ctxP = (bf16*)(ws + off);
    bf16* xz   = ctxP;                                   // 17.2 MB
    bf16* xr   = ctxP + (size_t)B_ * IPX * 64;           // 17.2 MB (fits in 45.1)
    off += (size_t)B_ * CTXC * HW_ * 2;
    // region 1: xctx (51.5 MB); after conv_q reused as xt1 + xt2
    bf16* xctx = (bf16*)(ws + off);
    bf16* xt1  = xctx;                                   // 17.2 MB (CP 64)
    bf16* xt2  = xctx + (size_t)B_ * IPX * 64;           // 12.9 MB (CP 48)
    off += (size_t)B_ * IPX * 192 * 2;
    bf16* xfeat = (bf16*)(ws + off); off += (size_t)B_ * IPX * 64 * 2;   // 17.2 MB
    bf16* xt    = (bf16*)(ws + off); off += (size_t)B_ * IPX * 64 * 2;   // 17.2 MB
    float* dscf = (float*)(ws + off); off += (size_t)4 * NPIX * 4;       // 2.1 MB
    bf16* wfz = (bf16*)(ws + off); off += 9*8*4*64*8 * 2;
    bf16* wfr = (bf16*)(ws + off); off += 9*8*4*64*8 * 2;
    bf16* wfq = (bf16*)(ws + off); off += 9*8*4*64*8 * 2;
    bf16* wf1 = (bf16*)(ws + off); off += 9*2*3*64*8 * 2;
    bf16* wf2 = (bf16*)(ws + off); off += 9*2*3*64*8 * 2;
    bf16*  sprm  = (bf16*)(ws + off); off += 1536;
    float* gpart = (float*)(ws + off); off += 512 * 4;
    float* gstat = (float*)(ws + off); off += 64 * 4;
    int*   flag  = (int*)(ws + off);   off += 256;

    detect_k<<<1, 64, 0, stream>>>((const unsigned int*)d_in[4], flag);

    // ---- weight/param staging (dual dtype; mismatched variant early-outs) ----
    wfrag_gru<bf16 ><<<576, 256, 0, stream>>>(flag, (const bf16*)d_in[7],  wfz);
    wfrag_gru<float><<<576, 256, 0, stream>>>(flag, (const float*)d_in[7], wfz);
    wfrag_gru<bf16 ><<<576, 256, 0, stream>>>(flag, (const bf16*)d_in[9],  wfr);
    wfrag_gru<float><<<576, 256, 0, stream>>>(flag, (const float*)d_in[9], wfr);
    wfrag_gru<bf16 ><<<576, 256, 0, stream>>>(flag, (const bf16*)d_in[11],  wfq);
    wfrag_gru<float><<<576, 256, 0, stream>>>(flag, (const float*)d_in[11], wfq);
    wfrag_trunk<bf16 ><<<108, 256, 0, stream>>>(flag, (const bf16*)d_in[13],  wf1, 64);
    wfrag_trunk<float><<<108, 256, 0, stream>>>(flag, (const float*)d_in[13], wf1, 64);
    wfrag_trunk<bf16 ><<<108, 256, 0, stream>>>(flag, (const bf16*)d_in[16],  wf2, 48);
    wfrag_trunk<float><<<108, 256, 0, stream>>>(flag, (const float*)d_in[16], wf2, 48);
    cvt_small<bf16><<<3, 256, 0, stream>>>(flag,
        (const bf16*)d_in[8], (const bf16*)d_in[10], (const bf16*)d_in[12],
        (const bf16*)d_in[14], (const bf16*)d_in[15], (const bf16*)d_in[17], (const bf16*)d_in[18],
        (const bf16*)d_in[19], (const bf16*)d_in[21], (const bf16*)d_in[23], (const bf16*)d_in[25],
        (const bf16*)d_in[20], (const bf16*)d_in[22], (const bf16*)d_in[24], (const bf16*)d_in[26],
        sprm);
    cvt_small<float><<<3, 256, 0, stream>>>(flag,
        (const float*)d_in[8], (const float*)d_in[10], (const float*)d_in[12],
        (const float*)d_in[14], (const float*)d_in[15], (const float*)d_in[17], (const float*)d_in[18],
        (const float*)d_in[19], (const float*)d_in[21], (const float*)d_in[23], (const float*)d_in[25],
        (const float*)d_in[20], (const float*)d_in[22], (const float*)d_in[24], (const float*)d_in[26],
        sprm);

    // ---- ctx + input staging ----
    build_ctx<bf16 ><<<B_ * H_, 256, 0, stream>>>(flag,
        (const bf16*)d_in[0], (const bf16*)d_in[1], (const bf16*)d_in[2],
        (const bf16*)d_in[3], (const bf16*)d_in[5], (const bf16*)d_in[6], ctxP, dscf);
    build_ctx<float><<<B_ * H_, 256, 0, stream>>>(flag,
        (const float*)d_in[0], (const float*)d_in[1], (const float*)d_in[2],
        (const float*)d_in[3], (const float*)d_in[5], (const float*)d_in[6], ctxP, dscf);
    to_nhwc_ctx<<<B_ * H_ * 2, 256, 0, stream>>>(ctxP, xctx);
    to_nhwc_in<bf16 ><<<B_ * H_ * 2, 256, 0, stream>>>(flag, (const bf16*)d_in[4],  xfeat);
    to_nhwc_in<float><<<B_ * H_ * 2, 256, 0, stream>>>(flag, (const float*)d_in[4], xfeat);
    zero_halo<<<B_ * RH, 256, 0, stream>>>(xctx, 192);
    zero_halo<<<B_ * RH, 256, 0, stream>>>(xfeat, 64);
    zero_halo<<<B_ * RH, 256, 0, stream>>>(xt, 64);

    // ---- GRU convs (MFMA) ----  (note: xz/xr alias ctxP, dead after to_nhwc_ctx)
    conv_mfma<6, 2, 4, 0><<<B_ * H_, 256, 0, stream>>>(xctx, xfeat, wfz, sprm + 0,
        xz, nullptr, nullptr, nullptr, flag, 192, 64);
    conv_mfma<6, 2, 4, 0><<<B_ * H_, 256, 0, stream>>>(xctx, xfeat, wfr, sprm + 64,
        xr, nullptr, nullptr, nullptr, flag, 192, 64);
    rfeat_nhwc<<<(B_ * IPX * 64 / 2 + 255) / 256, 256, 0, stream>>>(xr, xfeat,
        B_ * IPX * 64 / 2);
    conv_mfma<6, 2, 4, 1><<<B_ * H_, 256, 0, stream>>>(xctx, xr, wfq, sprm + 128,
        xt, xz, xfeat, d_out, flag, 192, 64);

    // ---- trunk (xt1/xt2 alias xctx, dead after conv_q) ----
    zero_full<<<(B_ * IPX * 64 / 8 + 255) / 256, 256, 0, stream>>>(xt1, B_ * IPX * 64 / 8);
    zero_halo<<<B_ * RH, 256, 0, stream>>>(xt2, 48);
    conv_mfma<2, 0, 3, 2><<<B_ * H_, 256, 0, stream>>>(xt, nullptr, wf1, sprm,
        xt1, nullptr, nullptr, nullptr, flag, 64, 64);
    gn_reduce_nhwc<<<256, 256, 0, stream>>>(xt1, gpart, 64);
    gn_finalize<<<1, 32, 0, stream>>>(gpart, gstat);
    gn_apply_nhwc<<<B_ * H_, 256, 0, stream>>>(xt1, gstat, sprm + 192, 64);

    conv_mfma<2, 0, 3, 2><<<B_ * H_, 256, 0, stream>>>(xt1, nullptr, wf2, sprm,
        xt2, nullptr, nullptr, nullptr, flag, 64, 48);
    gn_reduce_nhwc<<<256, 256, 0, stream>>>(xt2, gpart, 48);
    gn_finalize<<<1, 32, 0, stream>>>(gpart, gstat);
    gn_apply_nhwc<<<B_ * H_, 256, 0, stream>>>(xt2, gstat, sprm + 288, 48);

    heads_k<<<B_ * H_, 256, 0, stream>>>(xt2, sprm, dscf, d_out, flag);
}

// Round 5
// 645.973 us; speedup vs baseline: 4.7409x; 1.4734x over previous
//
#include <hip/hip_runtime.h>
#include <hip/hip_bf16.h>
#include <math.h>
#include <type_traits>

typedef __hip_bfloat16 bf16;
typedef __attribute__((ext_vector_type(8))) short bf16x8;
typedef __attribute__((ext_vector_type(4))) float f32x4;

#define B_    4
#define H_    128
#define W_    256
#define HW_   32768          // H_*W_
#define CTXC  172
#define NPIX  131072         // B_*HW_
#define RW    258            // W_+2 (halo row width)
#define RH    130            // H_+2
#define IPX   33540          // RW*RH pixels per image (halo incl.)

__device__ __forceinline__ float b2f(bf16 v) { return __bfloat162float(v); }
__device__ __forceinline__ bf16  f2b(float v){ return __float2bfloat16(v); }
__device__ __forceinline__ unsigned short f2bu(float v){ bf16 h = f2b(v); return *(unsigned short*)&h; }
__device__ __forceinline__ float ldv(const float* p){ return *p; }
__device__ __forceinline__ float ldv(const bf16* p) { return b2f(*p); }

// ------------------------------------------------------------- dtype detect --
__global__ void detect_k(const unsigned int* __restrict__ feat_raw,
                         int* __restrict__ flag)
{
    if (threadIdx.x != 0 || blockIdx.x != 0) return;
    int hits = 0;
    for (int i = 0; i < 64; ++i) {
        unsigned int w = feat_raw[i];
        unsigned int e = (w >> 7) & 0xFFu;
        hits += (e >= 0xC0u) ? 1 : 0;
    }
    *flag = (hits > 0) ? 1 : 0;
}

template<typename IT>
__device__ __forceinline__ bool gate_skip(const int* flag)
{
    constexpr bool isf = std::is_same<IT, float>::value;
    return (*flag != 0) != isf;
}

// ---------------------------------------------------- weight fragment shuffle
// GRU conv weights [64][236][3][3] -> B-fragment order.
// K-order per tap: k 0..191 = ctx channel k (orig ci=64+k; k>=172 zero),
//                  k 192..255 = feat channel (orig ci=k-192).
template<typename IT>
__global__ __launch_bounds__(256) void wfrag_gru(const int* __restrict__ flag,
                                                 const IT* __restrict__ src,
                                                 bf16* __restrict__ dst)
{
    if (gate_skip<IT>(flag)) return;
    int i = blockIdx.x * 256 + threadIdx.x;
    if (i >= 9*8*4*64*8) return;
    int j    = i & 7;
    int lane = (i >> 3) & 63;
    int u    = (i >> 9) & 3;
    int s    = (i >> 11) & 7;
    int t    = i >> 14;
    int klocal = ((lane >> 4) << 3) + j;
    int co = u * 16 + (lane & 15);
    float v = 0.f;
    if (s < 6) {
        int k = s * 32 + klocal;
        if (k < CTXC) v = ldv(src + ((size_t)co * 236 + 64 + k) * 9 + t);
    } else {
        int kf = (s - 6) * 32 + klocal;
        v = ldv(src + ((size_t)co * 236 + kf) * 9 + t);
    }
    dst[i] = f2b(v);
}

// trunk weights [48][CIN][3][3] -> frag order, Kpad=64 (2 ksteps), NT=3
template<typename IT>
__global__ __launch_bounds__(256) void wfrag_trunk(const int* __restrict__ flag,
                                                   const IT* __restrict__ src,
                                                   bf16* __restrict__ dst, int CIN)
{
    if (gate_skip<IT>(flag)) return;
    int i = blockIdx.x * 256 + threadIdx.x;
    if (i >= 9*2*3*64*8) return;
    int j    = i & 7;
    int lane = (i >> 3) & 63;
    int rest = i >> 9;
    int u = rest % 3; rest /= 3;
    int s = rest & 1;
    int t = rest >> 1;
    int k = s * 32 + ((lane >> 4) << 3) + j;
    int co = u * 16 + (lane & 15);
    float v = (k < CIN) ? ldv(src + ((size_t)co * CIN + k) * 9 + t) : 0.f;
    dst[i] = f2b(v);
}

// small params: 0:zb 64:rb 128:qb 192:g1s 240:g1b 288:g2s 336:g2b
// 384:wd 432:wx 480:wy 528:wc 576:bd 577:bx 578:by 579:bc
template<typename IT>
__global__ void cvt_small(const int* __restrict__ flag,
    const IT* zb, const IT* rb, const IT* qb,
    const IT* g1s, const IT* g1b, const IT* g2s, const IT* g2b,
    const IT* wd, const IT* wx, const IT* wy, const IT* wc,
    const IT* bd, const IT* bx, const IT* by, const IT* bc,
    bf16* __restrict__ dst)
{
    if (gate_skip<IT>(flag)) return;
    int i = blockIdx.x * 256 + threadIdx.x;
    if (i >= 580) return;
    const IT* src; int off;
    if      (i < 64)  { src = zb;  off = i; }
    else if (i < 128) { src = rb;  off = i - 64; }
    else if (i < 192) { src = qb;  off = i - 128; }
    else if (i < 240) { src = g1s; off = i - 192; }
    else if (i < 288) { src = g1b; off = i - 240; }
    else if (i < 336) { src = g2s; off = i - 288; }
    else if (i < 384) { src = g2b; off = i - 336; }
    else if (i < 432) { src = wd;  off = i - 384; }
    else if (i < 480) { src = wx;  off = i - 432; }
    else if (i < 528) { src = wy;  off = i - 480; }
    else if (i < 576) { src = wc;  off = i - 528; }
    else if (i == 576){ src = bd;  off = 0; }
    else if (i == 577){ src = bx;  off = 0; }
    else if (i == 578){ src = by;  off = 0; }
    else              { src = bc;  off = 0; }
    dst[i] = f2b(ldv(src + off));
}

// ------------------------------------------------------------------- ctx -----
// Writes xin NHWC record [B][RH][RW][256]:
//   ch 0..63 fL, 64..127 fR_w, 128 d, 129 sx, 130 sy, 131 conf,
//   132..171 cost, 172..191 zero, 192..255 feat.
template<typename IT>
__global__ __launch_bounds__(256) void build_ctx_nhwc(
    const int* __restrict__ flag,
    const IT* __restrict__ d_, const IT* __restrict__ sx_,
    const IT* __restrict__ sy_, const IT* __restrict__ conf_,
    const IT* __restrict__ fL, const IT* __restrict__ fR,
    const IT* __restrict__ feat,
    bf16* __restrict__ xin, float* __restrict__ dscf)
{
    if (gate_skip<IT>(flag)) return;
    const int x   = threadIdx.x;
    const int y   = blockIdx.x & (H_ - 1);
    const int b   = blockIdx.x >> 7;
    const int pix = (b << 15) | (y << 8) | x;

    const float d0 = ldv(d_ + pix);

    float xw = fminf(fmaxf((float)x - d0, 0.f), (float)(W_ - 1));
    float x0f = floorf(xw);
    float w1 = xw - x0f;
    int i0 = (int)x0f;
    int i1 = min(i0 + 1, W_ - 1);

    int   j0[5], j1[5];
    float wq[5];
#pragma unroll
    for (int dd = 0; dd < 5; ++dd) {
        float cd = fminf(fmaxf((float)x - d0 - (float)(dd - 2), 0.f), (float)(W_ - 1));
        float c0 = floorf(cd);
        wq[dd] = cd - c0;
        j0[dd] = (int)c0;
        j1[dd] = min(j0[dd] + 1, W_ - 1);
    }

    float cost[40];
#pragma unroll
    for (int k = 0; k < 40; ++k) cost[k] = 0.f;

    const IT* fLrow = fL + (size_t)b * 64 * HW_ + y * W_;
    const IT* fRrow = fR + (size_t)b * 64 * HW_ + y * W_;
    bf16* rec = xin + ((size_t)(b * RH + y + 1) * RW + 1 + x) * 256;

    unsigned short bufL[8], bufW[8];
#pragma unroll
    for (int c = 0; c < 64; ++c) {
        const IT* fr = fRrow + (size_t)c * HW_;
        float fl = ldv(fLrow + (size_t)c * HW_ + x);
        float fw = ldv(fr + i0) * (1.f - w1) + ldv(fr + i1) * w1;
        bufL[c & 7] = f2bu(fl);
        bufW[c & 7] = f2bu(fw);
        const int g = c >> 3;
#pragma unroll
        for (int dd = 0; dd < 5; ++dd) {
            float s = ldv(fr + j0[dd]) * (1.f - wq[dd]) + ldv(fr + j1[dd]) * wq[dd];
            cost[g * 5 + dd] = fmaf(fl, s, cost[g * 5 + dd]);
        }
        if ((c & 7) == 7) {
            *(uint4*)(rec + (c - 7))      = *(uint4*)bufL;
            *(uint4*)(rec + 64 + (c - 7)) = *(uint4*)bufW;
        }
    }

    float sxv = ldv(sx_ + pix);
    float syv = ldv(sy_ + pix);
    float cfv = ldv(conf_ + pix);

    // ch 128..175: d,sx,sy,conf,cost*0.125(40),0,0,0,0
    {
        unsigned short t8[8];
        t8[0] = f2bu(d0);  t8[1] = f2bu(sxv);
        t8[2] = f2bu(syv); t8[3] = f2bu(cfv);
#pragma unroll
        for (int k = 0; k < 4; ++k) t8[4 + k] = f2bu(cost[k] * 0.125f);
        *(uint4*)(rec + 128) = *(uint4*)t8;
#pragma unroll
        for (int ch = 1; ch < 6; ++ch) {
#pragma unroll
            for (int k = 0; k < 8; ++k) {
                int ci = ch * 8 - 4 + k;           // cost index 4..43
                t8[k] = (ci < 40) ? f2bu(cost[ci] * 0.125f) : 0;
            }
            *(uint4*)(rec + 128 + ch * 8) = *(uint4*)t8;
        }
    }
    // ch 176..191 zero
    {
        uint4 z = {0u, 0u, 0u, 0u};
        *(uint4*)(rec + 176) = z;
        *(uint4*)(rec + 184) = z;
    }
    // ch 192..255 feat
    {
        const IT* fts = feat + (size_t)b * 64 * HW_ + y * W_ + x;
        unsigned short t8[8];
#pragma unroll
        for (int c = 0; c < 64; ++c) {
            t8[c & 7] = f2bu(ldv(fts + (size_t)c * HW_));
            if ((c & 7) == 7) *(uint4*)(rec + 192 + (c - 7)) = *(uint4*)t8;
        }
    }

    dscf[pix]            = d0;
    dscf[NPIX + pix]     = sxv;
    dscf[2 * NPIX + pix] = syv;
    dscf[3 * NPIX + pix] = cfv;
}

// ----------------------------------------------------------------- zeroing ---
__global__ __launch_bounds__(256) void zero_halo(bf16* __restrict__ buf, int CP)
{
    int yy = blockIdx.x % RH;
    int b  = blockIdx.x / RH;
    for (int x = threadIdx.x; x < RW; x += 256) {
        bool h = (yy == 0) | (yy == RH - 1) | (x == 0) | (x == RW - 1);
        if (!h) continue;
        bf16* p = buf + ((size_t)(b * RH + yy) * RW + x) * CP;
        uint4 z = {0u, 0u, 0u, 0u};
        for (int c = 0; c < CP; c += 8)
            *(uint4*)(p + c) = z;
    }
}

__global__ __launch_bounds__(256) void zero_full(bf16* __restrict__ buf, int n16)
{
    int i = blockIdx.x * 256 + threadIdx.x;
    if (i >= n16) return;
    uint4 z = {0u, 0u, 0u, 0u};
    *(uint4*)(buf + (size_t)i * 8) = z;
}

// -------------------------------------------------- LDS-tiled MFMA 3x3 conv --
// Block = 64x4 output tile (4 waves, one row each). Chunks of 64 ch staged in
// LDS (XOR-swizzled 16B units -> conflict-free ds_read_b128 / ds_write_b128).
// NCH: 64-ch chunks (4 for GRU/256ch, 1 for trunk/64ch).
// MODE 0: sigmoid(acc+bias) -> outn            (conv_z)
// MODE 3: sigmoid(acc+bias)*feat -> outn       (conv_r, feat from srcA ch192+n)
// MODE 1: GRU combine -> outn(xt) + d_out slot3; chunk 3 staged from srcB (xr)
// MODE 2: plain -> outn                        (trunk)
template<int NCH, int NT, int MODE>
__global__ __launch_bounds__(256) void conv_tile(
    const bf16* __restrict__ srcA, const bf16* __restrict__ srcB,
    const bf16* __restrict__ wfrag, const bf16* __restrict__ bias,
    bf16* __restrict__ outn, int CPO,
    const bf16* __restrict__ xz,
    void* __restrict__ dout, const int* __restrict__ flag)
{
    constexpr int CPA = (NCH == 4) ? 256 : 64;
    __shared__ uint4 lds4[6 * 66 * 8];          // 50688 B

    const int tid  = threadIdx.x;
    const int lane = tid & 63;
    const int wv   = tid >> 6;
    const int m    = lane & 15;
    const int quad = lane >> 4;

    const int bx = blockIdx.x;
    const int x0 = (bx & 3) << 6;
    const int y0 = ((bx >> 2) & 31) << 2;
    const int b  = bx >> 7;

    f32x4 acc[4][NT];
#pragma unroll
    for (int mt = 0; mt < 4; ++mt)
#pragma unroll
        for (int u = 0; u < NT; ++u)
            acc[mt][u] = (f32x4){0.f, 0.f, 0.f, 0.f};

    const size_t tileBase = (size_t)(b * RH + y0) * RW + x0;  // input-tile origin

    for (int ch = 0; ch < NCH; ++ch) {
        if (ch) __syncthreads();
        const bool useB = (MODE == 1) && (ch == 3);
        const bf16* gsrc = useB ? srcB : srcA;
        const int cpg  = useB ? 64 : CPA;
        const int cofs = useB ? 0 : ch * 64;
        for (int idx = tid; idx < 3168; idx += 256) {
            const int part = idx & 7;
            const int rp   = idx >> 3;
            const int rr   = rp / 66;
            const int cc   = rp - rr * 66;
            const uint4 v = *(const uint4*)(gsrc +
                (tileBase + (size_t)rr * RW + cc) * cpg + cofs + part * 8);
            lds4[rp * 8 + (part ^ (cc & 7))] = v;
        }
        __syncthreads();
#pragma unroll
        for (int t = 0; t < 9; ++t) {
            const int dy = t / 3, dx = t % 3;
#pragma unroll
            for (int s = 0; s < 2; ++s) {
                bf16x8 a[4];
#pragma unroll
                for (int mt = 0; mt < 4; ++mt) {
                    const int cc = mt * 16 + m + dx;
                    const int j  = (s * 4 + quad) ^ (cc & 7);
                    a[mt] = ((const bf16x8*)lds4)[((wv + dy) * 66 + cc) * 8 + j];
                }
#pragma unroll
                for (int u = 0; u < NT; ++u) {
                    bf16x8 bw = *(const bf16x8*)(wfrag +
                        ((size_t)(((t * (NCH * 2) + ch * 2 + s) * NT + u) * 64 + lane) << 3));
#pragma unroll
                    for (int mt = 0; mt < 4; ++mt)
                        acc[mt][u] = __builtin_amdgcn_mfma_f32_16x16x32_bf16(
                            a[mt], bw, acc[mt][u], 0, 0, 0);
                }
            }
        }
    }

    const int gy = y0 + wv;                       // output row 0..127
    const size_t rec0 = (size_t)(b * RH + gy + 1) * RW + 1 + x0;
#pragma unroll
    for (int mt = 0; mt < 4; ++mt) {
        const int px0 = mt * 16 + quad * 4;
#pragma unroll
        for (int u = 0; u < NT; ++u) {
            const int n = u * 16 + m;
            if (MODE == 0) {
                float bn = b2f(bias[n]);
#pragma unroll
                for (int r = 0; r < 4; ++r) {
                    float v = acc[mt][u][r] + bn;
                    outn[(rec0 + px0 + r) * CPO + n] = f2b(1.f / (1.f + expf(-v)));
                }
            } else if (MODE == 3) {
                float bn = b2f(bias[n]);
#pragma unroll
                for (int r = 0; r < 4; ++r) {
                    float v = acc[mt][u][r] + bn;
                    float sg = 1.f / (1.f + expf(-v));
                    float fv = b2f(srcA[(rec0 + px0 + r) * 256 + 192 + n]);
                    outn[(rec0 + px0 + r) * CPO + n] = f2b(sg * fv);
                }
            } else if (MODE == 2) {
#pragma unroll
                for (int r = 0; r < 4; ++r)
                    outn[(rec0 + px0 + r) * CPO + n] = f2b(acc[mt][u][r]);
            } else {
                float bn = b2f(bias[n]);
                float hv[4];
#pragma unroll
                for (int r = 0; r < 4; ++r) {
                    float q = tanhf(acc[mt][u][r] + bn);
                    size_t ai = (rec0 + px0 + r) * 64 + n;
                    float zv = b2f(xz[ai]);
                    float fv = b2f(srcA[(rec0 + px0 + r) * 256 + 192 + n]);
                    hv[r] = (1.f - zv) * fv + zv * q;
                    outn[ai] = f2b(hv[r]);
                }
                size_t pb = ((size_t)(b * 64 + n) << 15) + gy * W_ + x0 + px0;
                if (*flag) {
                    float4 o; o.x = hv[0]; o.y = hv[1]; o.z = hv[2]; o.w = hv[3];
                    *(float4*)((float*)dout + 393216 + pb) = o;
                } else {
                    ushort4 o;
                    o.x = f2bu(hv[0]); o.y = f2bu(hv[1]);
                    o.z = f2bu(hv[2]); o.w = f2bu(hv[3]);
                    *(ushort4*)((bf16*)dout + 393216 + pb) = o;
                }
            }
        }
    }
}

// -------------------------------------------------------------- groupnorm ----
__global__ __launch_bounds__(256) void gn_reduce_nhwc(const bf16* __restrict__ buf,
                                                      float* __restrict__ part, int CP)
{
    const int gp = blockIdx.x >> 3;     // b*8+g
    const int pt = blockIdx.x & 7;
    const int b = gp >> 3, g = gp & 7;
    const int lo = pt * 4193;
    const int hi = min(lo + 4193, IPX);
    const bf16* base = buf + (size_t)b * IPX * CP + g * 6;
    float s = 0.f, ss = 0.f;
    for (int px = lo + threadIdx.x; px < hi; px += 256) {
        const bf16* q = base + (size_t)px * CP;
#pragma unroll
        for (int c = 0; c < 6; ++c) {
            float v = b2f(q[c]);
            s += v;
            ss = fmaf(v, v, ss);
        }
    }
#pragma unroll
    for (int o = 32; o > 0; o >>= 1) {
        s  += __shfl_down(s, o, 64);
        ss += __shfl_down(ss, o, 64);
    }
    __shared__ float sm[8];
    int wid = threadIdx.x >> 6;
    if ((threadIdx.x & 63) == 0) { sm[wid * 2] = s; sm[wid * 2 + 1] = ss; }
    __syncthreads();
    if (threadIdx.x == 0) {
        float S = 0.f, SS = 0.f;
        for (int i = 0; i < 4; ++i) { S += sm[i * 2]; SS += sm[i * 2 + 1]; }
        part[(gp * 8 + pt) * 2]     = S;
        part[(gp * 8 + pt) * 2 + 1] = SS;
    }
}

__global__ void gn_finalize(const float* __restrict__ part, float* __restrict__ stats)
{
    int gp = threadIdx.x;
    if (gp >= 32) return;
    float S = 0.f, SS = 0.f;
    for (int i = 0; i < 8; ++i) {
        S  += part[(gp * 8 + i) * 2];
        SS += part[(gp * 8 + i) * 2 + 1];
    }
    const float N = 6.f * HW_;
    float mn  = S / N;
    float var = SS / N - mn * mn;
    var = fmaxf(var, 0.f);
    stats[gp * 2]     = mn;
    stats[gp * 2 + 1] = rsqrtf(var + 1e-5f);
}

__global__ __launch_bounds__(256) void gn_apply_nhwc(bf16* __restrict__ buf,
                                                     const float* __restrict__ stats,
                                                     const bf16* __restrict__ scbi,
                                                     int CP)
{
    const int y = blockIdx.x & (H_ - 1);
    const int b = blockIdx.x >> 7;
    bf16* base = buf + ((size_t)(b * RH + y + 1) * RW + 1) * CP;
    for (int j = threadIdx.x; j < W_ * 48; j += 256) {
        int px = j / 48;
        int c  = j - px * 48;
        int g  = c / 6;
        float mn = stats[(b * 8 + g) * 2], rr = stats[(b * 8 + g) * 2 + 1];
        size_t idx = (size_t)px * CP + c;
        float v = (b2f(base[idx]) - mn) * rr * b2f(scbi[c]) + b2f(scbi[48 + c]);
        base[idx] = f2b(v / (1.f + expf(-v)));
    }
}

// ------------------------------------------------------------------ heads ----
__global__ __launch_bounds__(256) void heads_k(
    const bf16* __restrict__ xt2,      // NHWC stride 48
    const bf16* __restrict__ sp,
    const float* __restrict__ dscf,
    void* __restrict__ out_base,
    const int* __restrict__ flag)
{
    const int x = threadIdx.x;
    const int y = blockIdx.x & (H_ - 1);
    const int b = blockIdx.x >> 7;
    const int pix = (b << 15) | (y << 8) | x;
    const bf16* t = xt2 + ((size_t)(b * RH + y + 1) * RW + 1 + x) * 48;
    float ad = 0.f, ax = 0.f, ay = 0.f, ac = 0.f;
#pragma unroll
    for (int c = 0; c < 48; ++c) {
        float v = b2f(t[c]);
        ad = fmaf(v, b2f(sp[384 + c]), ad);
        ax = fmaf(v, b2f(sp[432 + c]), ax);
        ay = fmaf(v, b2f(sp[480 + c]), ay);
        ac = fmaf(v, b2f(sp[528 + c]), ac);
    }
    float dv  = dscf[pix];
    float sxv = dscf[NPIX + pix];
    float syv = dscf[2 * NPIX + pix];
    float cfv = dscf[3 * NPIX + pix];

    float dval = ad + b2f(sp[576]) + dv;
    float spv = fmaxf(dval, 0.f) + log1pf(expf(-fabsf(dval)));
    float sxo = sxv + 0.1f * (ax + b2f(sp[577]));
    float syo = syv + 0.1f * (ay + b2f(sp[578]));
    float cvv = 1.f / (1.f + expf(-(ac + b2f(sp[579]) + 2.f * cfv - 1.f)));

    if (*flag) {
        float* of = (float*)out_base;
        of[pix]            = spv;
        of[NPIX + pix]     = sxo;
        of[2 * NPIX + pix] = syo;
        of[8781824 + pix]  = cvv;
    } else {
        bf16* ob = (bf16*)out_base;
        ob[pix]            = f2b(spv);
        ob[NPIX + pix]     = f2b(sxo);
        ob[2 * NPIX + pix] = f2b(syo);
        ob[8781824 + pix]  = f2b(cvv);
    }
}

// ------------------------------------------------------------------ launch ---
extern "C" void kernel_launch(void* const* d_in, const int* in_sizes, int n_in,
                              void* d_out, int out_size, void* d_ws, size_t ws_size,
                              hipStream_t stream)
{
    char* ws = (char*)d_ws;
    size_t off = 0;
    bf16* xin = (bf16*)(ws + off); off += (size_t)B_ * IPX * 256 * 2;   // 68.7 MB
    bf16* xz  = (bf16*)(ws + off); off += (size_t)B_ * IPX * 64 * 2;    // 17.2 MB (later xt1)
    bf16* xr  = (bf16*)(ws + off); off += (size_t)B_ * IPX * 64 * 2;    // 17.2 MB (later xt2, CP48)
    bf16* xt  = (bf16*)(ws + off); off += (size_t)B_ * IPX * 64 * 2;    // 17.2 MB (h_new)
    bf16* xt1 = xz;
    bf16* xt2 = xr;
    float* dscf = (float*)(ws + off); off += (size_t)4 * NPIX * 4;      // 2.1 MB
    bf16* wfz = (bf16*)(ws + off); off += 9*8*4*64*8 * 2;
    bf16* wfr = (bf16*)(ws + off); off += 9*8*4*64*8 * 2;
    bf16* wfq = (bf16*)(ws + off); off += 9*8*4*64*8 * 2;
    bf16* wf1 = (bf16*)(ws + off); off += 9*2*3*64*8 * 2;
    bf16* wf2 = (bf16*)(ws + off); off += 9*2*3*64*8 * 2;
    bf16*  sprm  = (bf16*)(ws + off); off += 1536;
    float* gpart = (float*)(ws + off); off += 512 * 4;
    float* gstat = (float*)(ws + off); off += 64 * 4;
    int*   flag  = (int*)(ws + off);   off += 256;

    detect_k<<<1, 64, 0, stream>>>((const unsigned int*)d_in[4], flag);

    // ---- weight/param staging (dual dtype; mismatched variant early-outs) ----
    wfrag_gru<bf16 ><<<576, 256, 0, stream>>>(flag, (const bf16*)d_in[7],  wfz);
    wfrag_gru<float><<<576, 256, 0, stream>>>(flag, (const float*)d_in[7], wfz);
    wfrag_gru<bf16 ><<<576, 256, 0, stream>>>(flag, (const bf16*)d_in[9],  wfr);
    wfrag_gru<float><<<576, 256, 0, stream>>>(flag, (const float*)d_in[9], wfr);
    wfrag_gru<bf16 ><<<576, 256, 0, stream>>>(flag, (const bf16*)d_in[11],  wfq);
    wfrag_gru<float><<<576, 256, 0, stream>>>(flag, (const float*)d_in[11], wfq);
    wfrag_trunk<bf16 ><<<108, 256, 0, stream>>>(flag, (const bf16*)d_in[13],  wf1, 64);
    wfrag_trunk<float><<<108, 256, 0, stream>>>(flag, (const float*)d_in[13], wf1, 64);
    wfrag_trunk<bf16 ><<<108, 256, 0, stream>>>(flag, (const bf16*)d_in[16],  wf2, 48);
    wfrag_trunk<float><<<108, 256, 0, stream>>>(flag, (const float*)d_in[16], wf2, 48);
    cvt_small<bf16><<<3, 256, 0, stream>>>(flag,
        (const bf16*)d_in[8], (const bf16*)d_in[10], (const bf16*)d_in[12],
        (const bf16*)d_in[14], (const bf16*)d_in[15], (const bf16*)d_in[17], (const bf16*)d_in[18],
        (const bf16*)d_in[19], (const bf16*)d_in[21], (const bf16*)d_in[23], (const bf16*)d_in[25],
        (const bf16*)d_in[20], (const bf16*)d_in[22], (const bf16*)d_in[24], (const bf16*)d_in[26],
        sprm);
    cvt_small<float><<<3, 256, 0, stream>>>(flag,
        (const float*)d_in[8], (const float*)d_in[10], (const float*)d_in[12],
        (const float*)d_in[14], (const float*)d_in[15], (const float*)d_in[17], (const float*)d_in[18],
        (const float*)d_in[19], (const float*)d_in[21], (const float*)d_in[23], (const float*)d_in[25],
        (const float*)d_in[20], (const float*)d_in[22], (const float*)d_in[24], (const float*)d_in[26],
        sprm);

    // ---- halo zero + fused ctx/feat NHWC staging ----
    zero_halo<<<B_ * RH, 256, 0, stream>>>(xin, 256);
    zero_halo<<<B_ * RH, 256, 0, stream>>>(xr, 64);
    zero_halo<<<B_ * RH, 256, 0, stream>>>(xt, 64);
    build_ctx_nhwc<bf16 ><<<B_ * H_, 256, 0, stream>>>(flag,
        (const bf16*)d_in[0], (const bf16*)d_in[1], (const bf16*)d_in[2],
        (const bf16*)d_in[3], (const bf16*)d_in[5], (const bf16*)d_in[6],
        (const bf16*)d_in[4], xin, dscf);
    build_ctx_nhwc<float><<<B_ * H_, 256, 0, stream>>>(flag,
        (const float*)d_in[0], (const float*)d_in[1], (const float*)d_in[2],
        (const float*)d_in[3], (const float*)d_in[5], (const float*)d_in[6],
        (const float*)d_in[4], xin, dscf);

    // ---- GRU convs ----
    conv_tile<4, 4, 0><<<512, 256, 0, stream>>>(xin, nullptr, wfz, sprm + 0,
        xz, 64, nullptr, nullptr, flag);
    conv_tile<4, 4, 3><<<512, 256, 0, stream>>>(xin, nullptr, wfr, sprm + 64,
        xr, 64, nullptr, nullptr, flag);
    conv_tile<4, 4, 1><<<512, 256, 0, stream>>>(xin, xr, wfq, sprm + 128,
        xt, 64, xz, d_out, flag);

    // ---- trunk ----
    zero_full<<<(B_ * IPX * 64 / 8 + 255) / 256, 256, 0, stream>>>(xt1, B_ * IPX * 64 / 8);
    zero_halo<<<B_ * RH, 256, 0, stream>>>(xt2, 48);
    conv_tile<1, 3, 2><<<512, 256, 0, stream>>>(xt, nullptr, wf1, sprm,
        xt1, 64, nullptr, nullptr, flag);
    gn_reduce_nhwc<<<256, 256, 0, stream>>>(xt1, gpart, 64);
    gn_finalize<<<1, 32, 0, stream>>>(gpart, gstat);
    gn_apply_nhwc<<<B_ * H_, 256, 0, stream>>>(xt1, gstat, sprm + 192, 64);

    conv_tile<1, 3, 2><<<512, 256, 0, stream>>>(xt1, nullptr, wf2, sprm,
        xt2, 48, nullptr, nullptr, flag);
    gn_reduce_nhwc<<<256, 256, 0, stream>>>(xt2, gpart, 48);
    gn_finalize<<<1, 32, 0, stream>>>(gpart, gstat);
    gn_apply_nhwc<<<B_ * H_, 256, 0, stream>>>(xt2, gstat, sprm + 288, 48);

    heads_k<<<B_ * H_, 256, 0, stream>>>(xt2, sprm, dscf, d_out, flag);
}